// Round 7
// baseline (339.738 us; speedup 1.0000x reference)
//
#include <hip/hip_runtime.h>
#include <hip/hip_fp16.h>
#include <hip/hip_fp8.h>

// SumLayer: weighted logsumexp over E children per node.
// N=32768, E=32, B=256, MAX_ELS=65536.
//
// R6 = R5 with compile fix: __builtin_nontemporal_load/store require
// ext_vector_type (scalar/vector) pointers, not HIP_vector_type classes.
//
// Design. Established: random row-gathers run ~3.7 TB/s on the L2-miss
// path; duration ~ EA bytes. R2's "slicing gives zero affinity" test was
// confounded: its 4MB fp16 slice == entire XCD L2 (thrashed by meta/out
// streams). R5/R6 retries slice-residency with all three fixes:
//   - fp8 G stored SLICE-MAJOR: G[s][row][32 cols] -> 2MB per slice.
//   - slice chosen by PHYSICAL XCD id (s_getreg HW_REG_XCC_ID, m09-verified)
//     + per-slice atomic queues with 8-way stealing (exactly-once by
//     construction, immune to dispatcher block->XCD layout).
//   - P loads / out stores use nontemporal hints to protect L2 for G.
// If affinity holds: 268MB logical gather becomes L2 hits (~34.5 TB/s),
// main EA ~82MB. Numerics unchanged from R3/R4 (absmax 0.0625 < 0.107).

constexpr int NN = 32768;
constexpr int EE = 32;
constexpr int BB = 256;
constexpr int MAX_ELS = 65536;
constexpr int SLICES = 8;                       // 32 cols/slice
constexpr int NODES_PER_CHUNK = 16;
constexpr int NCHUNK = NN / NODES_PER_CHUNK;    // 2048
constexpr int TOTAL_ITEMS = SLICES * NCHUNK;    // 16384
constexpr int SLICE_U32 = MAX_ELS * 8;          // uints per 2MB G slice

typedef float floatx2 __attribute__((ext_vector_type(2)));
typedef float floatx4 __attribute__((ext_vector_type(4)));
typedef unsigned int uintx2 __attribute__((ext_vector_type(2)));

__device__ inline unsigned int pack4_fp8exp(float4 v) {
    const unsigned int a = __hip_cvt_float_to_fp8(__expf(v.x), __HIP_SATFINITE, __HIP_E4M3);
    const unsigned int b = __hip_cvt_float_to_fp8(__expf(v.y), __HIP_SATFINITE, __HIP_E4M3);
    const unsigned int c = __hip_cvt_float_to_fp8(__expf(v.z), __HIP_SATFINITE, __HIP_E4M3);
    const unsigned int d = __hip_cvt_float_to_fp8(__expf(v.w), __HIP_SATFINITE, __HIP_E4M3);
    return a | (b << 8) | (c << 16) | (d << 24);
}

// ---- zero the 8 work-queue counters (d_ws is poisoned every call) ----
__global__ void zero_ctrs_kernel(int* __restrict__ ctr) {
    if (threadIdx.x < 16) ctr[threadIdx.x] = 0;
}

// ---- pre-pass 1: G[s][r][qq] = fp8(exp(em[r][s*32+4qq..])), slice-major ----
__global__ __launch_bounds__(256)
void exp_convert_kernel(const float4* __restrict__ em, unsigned int* __restrict__ G)
{
    const int i  = blockIdx.x * 256 + threadIdx.x;  // col-quad id
    const int r  = i >> 6;                          // row
    const int cq = i & 63;                          // col-quad 0..63
    const float4 v = em[i];
    const int s  = cq >> 3;
    const int qq = cq & 7;
    G[s * SLICE_U32 + r * 8 + qq] = pack4_fp8exp(v);
}

// ---- pre-pass 2: P[i] = cids[i] | fp16(params[pids[i]]) << 16 ----
__global__ __launch_bounds__(256)
void pack_kernel(const float* __restrict__ params, const int* __restrict__ pids,
                 const int* __restrict__ cids, unsigned int* __restrict__ P)
{
    const int i = blockIdx.x * 256 + threadIdx.x;
    const unsigned int cid = (unsigned int)cids[i];            // < 65536
    const unsigned short wb = __half_as_ushort(__float2half(params[pids[i]]));
    P[i] = cid | ((unsigned int)wb << 16);
}

// ---- main: XCD-resident slice gather ----
__global__ __launch_bounds__(256)
void sum_main_kernel(const unsigned int* __restrict__ G,
                     const unsigned int* __restrict__ P,
                     const int* __restrict__ nids,
                     int* __restrict__ ctr,
                     float* __restrict__ out)
{
    __shared__ int s_item;
    __shared__ unsigned int s_pk[NODES_PER_CHUNK * EE];   // 2KB

    if (threadIdx.x == 0) {
        // hwreg(HW_REG_XCC_ID=20, offset=0, size=4) -> imm 6164
        const int xcc = __builtin_amdgcn_s_getreg(6164) & (SLICES - 1);
        int item = -1;
        for (int a = 0; a < SLICES; ++a) {
            const int s = (xcc + a) & (SLICES - 1);
            const int c = atomicAdd(&ctr[s], 1);
            if (c < NCHUNK) { item = s * NCHUNK + c; break; }
        }
        s_item = item;
    }
    __syncthreads();
    const int item = s_item;
    if (item < 0) return;                 // all work claimed
    const int s = item >> 11;             // item / NCHUNK
    const int c = item & (NCHUNK - 1);

    const int tid = threadIdx.x;
    const int base_n = c * NODES_PER_CHUNK;

    // stage this chunk's packed (cid,w): 512 uints, nontemporal
    const uintx2 pv = __builtin_nontemporal_load(
        (const uintx2*)(P + (size_t)base_n * EE) + tid);
    s_pk[2 * tid]     = pv.x;
    s_pk[2 * tid + 1] = pv.y;
    __syncthreads();

    const int wv = tid >> 6, lane = tid & 63;
    const int g = lane >> 3;              // child octet (bits 3..5)
    const int q = lane & 7;               // col-quad within slice
    const unsigned int* Gs = G + (size_t)s * SLICE_U32;

    for (int j = 0; j < 4; ++j) {
        const int nl = wv * 4 + j;        // node within chunk
        float4 acc = make_float4(0.f, 0.f, 0.f, 0.f);
#pragma unroll
        for (int k = 0; k < 4; ++k) {
            const unsigned int pk = s_pk[nl * EE + k * 8 + g];
            const float w = __half2float(__ushort_as_half((unsigned short)(pk >> 16)));
            // 8 lanes (q=0..7) read one contiguous 32B row-slice
            const unsigned int u = Gs[(size_t)(pk & 0xFFFFu) * 8 + q];
            const floatx2 lo = __builtin_amdgcn_cvt_pk_f32_fp8(u, false);
            const floatx2 hi = __builtin_amdgcn_cvt_pk_f32_fp8(u, true);
            acc.x = fmaf(lo.x, w, acc.x);
            acc.y = fmaf(lo.y, w, acc.y);
            acc.z = fmaf(hi.x, w, acc.z);
            acc.w = fmaf(hi.y, w, acc.w);
        }
        // reduce over child octets (lane bits 3,4,5)
#pragma unroll
        for (int m = 8; m <= 32; m <<= 1) {
            acc.x += __shfl_xor(acc.x, m);
            acc.y += __shfl_xor(acc.y, m);
            acc.z += __shfl_xor(acc.z, m);
            acc.w += __shfl_xor(acc.w, m);
        }
        if (g == 0) {
            const int n = base_n + nl;
            floatx4 r;
            r.x = __logf(fmaxf(acc.x, 1e-10f));
            r.y = __logf(fmaxf(acc.y, 1e-10f));
            r.z = __logf(fmaxf(acc.z, 1e-10f));
            r.w = __logf(fmaxf(acc.w, 1e-10f));
            __builtin_nontemporal_store(r,
                (floatx4*)(out + (size_t)nids[n] * BB + s * 32) + q);
        }
    }
}

// ---- fallback (ws too small): standalone fp32 version ----
__global__ __launch_bounds__(256, 2)
void sum_layer_fallback(const float* __restrict__ element_mars,
                        const float* __restrict__ params,
                        const int* __restrict__ nids,
                        const int* __restrict__ cids,
                        const int* __restrict__ pids,
                        float* __restrict__ out)
{
    const int tid  = threadIdx.x;
    const int wave = tid >> 6;
    const int lane = tid & 63;

    __shared__ int   s_cid[4][EE];
    __shared__ float s_w[4][EE];
    if (tid < 4 * EE) {
        const int wi = tid >> 5, e = tid & (EE - 1);
        const int gn = blockIdx.x * 4 + wi;
        s_cid[wi][e] = cids[gn * EE + e];
        s_w[wi][e]   = params[pids[gn * EE + e]];
    }
    __syncthreads();

    const int n = blockIdx.x * 4 + wave;
    float4 acc = make_float4(0.f, 0.f, 0.f, 0.f);
#pragma unroll
    for (int e = 0; e < EE; ++e) {
        const float4 v = *reinterpret_cast<const float4*>(
            element_mars + (size_t)s_cid[wave][e] * BB + 4 * lane);
        const float w = s_w[wave][e];
        acc.x = fmaf(__expf(v.x), w, acc.x);
        acc.y = fmaf(__expf(v.y), w, acc.y);
        acc.z = fmaf(__expf(v.z), w, acc.z);
        acc.w = fmaf(__expf(v.w), w, acc.w);
    }
    float4 r;
    r.x = __logf(fmaxf(acc.x, 1e-10f));
    r.y = __logf(fmaxf(acc.y, 1e-10f));
    r.z = __logf(fmaxf(acc.z, 1e-10f));
    r.w = __logf(fmaxf(acc.w, 1e-10f));
    *reinterpret_cast<float4*>(out + (size_t)nids[n] * BB + 4 * lane) = r;
}

extern "C" void kernel_launch(void* const* d_in, const int* in_sizes, int n_in,
                              void* d_out, int out_size, void* d_ws, size_t ws_size,
                              hipStream_t stream) {
    // inputs: node_mars[N,B], element_mars[MAX_ELS,B], params[N*E],
    //         nids[N], cids[N,E], pids[N,E]
    const float* element_mars = (const float*)d_in[1];
    const float* params       = (const float*)d_in[2];
    const int*   nids         = (const int*)d_in[3];
    const int*   cids         = (const int*)d_in[4];
    const int*   pids         = (const int*)d_in[5];
    float*       out          = (float*)d_out;

    const size_t g_bytes = (size_t)MAX_ELS * BB;                    // 16MB fp8
    const size_t p_bytes = (size_t)NN * EE * sizeof(unsigned int);  // 4MB packed
    const size_t c_bytes = 64;                                      // counters

    if (ws_size >= g_bytes + p_bytes + c_bytes) {
        unsigned int* G = (unsigned int*)d_ws;
        unsigned int* P = (unsigned int*)((char*)d_ws + g_bytes);
        int*        ctr = (int*)((char*)d_ws + g_bytes + p_bytes);

        zero_ctrs_kernel<<<1, 64, 0, stream>>>(ctr);
        exp_convert_kernel<<<(MAX_ELS * 64) / 256, 256, 0, stream>>>(
            (const float4*)element_mars, G);
        pack_kernel<<<(NN * EE) / 256, 256, 0, stream>>>(params, pids, cids, P);
        sum_main_kernel<<<TOTAL_ITEMS, 256, 0, stream>>>(G, P, nids, ctr, out);
    } else {
        sum_layer_fallback<<<NN / 4, 256, 0, stream>>>(
            element_mars, params, nids, cids, pids, out);
    }
}

// Round 8
// 200.138 us; speedup vs baseline: 1.6975x; 1.6975x over previous
//
#include <hip/hip_runtime.h>
#include <hip/hip_fp16.h>
#include <hip/hip_fp8.h>

// SumLayer: weighted logsumexp over E children per node.
// N=32768, E=32, B=256, MAX_ELS=65536.
//
// R7. Established facts:
//  - Random row-gathers from HBM/L3 run at a fixed ~3.7 TB/s L2-miss path.
//  - R6 proved XCD slice-residency WORKS: slice-major fp8 G (2MB/XCD-L2) +
//    physical-XCD work selection dropped main FETCH 210MB -> 25MB.
//  - R6's 199us regression was the work queue: 8 counters in ONE cache line,
//    ~16K blocks serializing device-scope RMWs on it (~12ns each ~= 200us).
// R7 fixes: counters padded to 128B apart; one atomic claims 8 chunks
// (grid 2048 blocks -> ~2048 atomics total, ~256/line, ~3us overlapped).
// Numerics unchanged (fp8 e4m3 of exp): absmax 0.0625 < 0.107 threshold.

constexpr int NN = 32768;
constexpr int EE = 32;
constexpr int BB = 256;
constexpr int MAX_ELS = 65536;
constexpr int SLICES = 8;                        // 32 cols/slice, 2MB fp8
constexpr int NODES_PER_CHUNK = 16;
constexpr int NCHUNK = NN / NODES_PER_CHUNK;     // 2048 chunks (global)
constexpr int CHUNKS_PER_CLAIM = 8;              // 128 nodes per claim
constexpr int NBLOCKS = SLICES * (NCHUNK / CHUNKS_PER_CLAIM);  // 2048
constexpr int SLICE_U32 = MAX_ELS * 8;           // uints per 2MB G slice
constexpr int CTR_STRIDE = 32;                   // 128B between counters

typedef float floatx2 __attribute__((ext_vector_type(2)));
typedef float floatx4 __attribute__((ext_vector_type(4)));
typedef unsigned int uintx4 __attribute__((ext_vector_type(4)));

__device__ inline unsigned int pack4_fp8exp(float4 v) {
    const unsigned int a = __hip_cvt_float_to_fp8(__expf(v.x), __HIP_SATFINITE, __HIP_E4M3);
    const unsigned int b = __hip_cvt_float_to_fp8(__expf(v.y), __HIP_SATFINITE, __HIP_E4M3);
    const unsigned int c = __hip_cvt_float_to_fp8(__expf(v.z), __HIP_SATFINITE, __HIP_E4M3);
    const unsigned int d = __hip_cvt_float_to_fp8(__expf(v.w), __HIP_SATFINITE, __HIP_E4M3);
    return a | (b << 8) | (c << 16) | (d << 24);
}

// ---- zero the padded work-queue counters (d_ws is poisoned every call) ----
__global__ void zero_ctrs_kernel(int* __restrict__ ctr) {
    ctr[threadIdx.x] = 0;   // 256 ints = 8 counters @ 128B stride
}

// ---- pre-pass 1: G[s][r][qq] = fp8(exp(em[r][s*32+4qq..])), slice-major ----
__global__ __launch_bounds__(256)
void exp_convert_kernel(const float4* __restrict__ em, unsigned int* __restrict__ G)
{
    const int i  = blockIdx.x * 256 + threadIdx.x;  // col-quad id
    const int r  = i >> 6;                          // row
    const int cq = i & 63;                          // col-quad 0..63
    const float4 v = em[i];
    const int s  = cq >> 3;
    const int qq = cq & 7;
    G[s * SLICE_U32 + r * 8 + qq] = pack4_fp8exp(v);
}

// ---- pre-pass 2: P[i] = cids[i] | fp16(params[pids[i]]) << 16 ----
__global__ __launch_bounds__(256)
void pack_kernel(const float* __restrict__ params, const int* __restrict__ pids,
                 const int* __restrict__ cids, unsigned int* __restrict__ P)
{
    const int i = blockIdx.x * 256 + threadIdx.x;
    const unsigned int cid = (unsigned int)cids[i];            // < 65536
    const unsigned short wb = __half_as_ushort(__float2half(params[pids[i]]));
    P[i] = cid | ((unsigned int)wb << 16);
}

// ---- main: XCD-resident slice gather, 8-chunk batches per block ----
__global__ __launch_bounds__(256)
void sum_main_kernel(const unsigned int* __restrict__ G,
                     const unsigned int* __restrict__ P,
                     const int* __restrict__ nids,
                     int* __restrict__ ctr,
                     float* __restrict__ out)
{
    __shared__ int s_item;
    // 8 chunks x 16 nodes x 32 children packed words = 16KB
    __shared__ unsigned int s_pk[CHUNKS_PER_CLAIM * NODES_PER_CHUNK * EE];

    const int tid = threadIdx.x;
    if (tid == 0) {
        // hwreg(HW_REG_XCC_ID=20, offset=0, size=4) -> imm 6164
        const int xcc = __builtin_amdgcn_s_getreg(6164) & (SLICES - 1);
        int item = -1;
        for (int a = 0; a < SLICES; ++a) {
            const int s = (xcc + a) & (SLICES - 1);
            const int c = atomicAdd(&ctr[s * CTR_STRIDE], CHUNKS_PER_CLAIM);
            if (c < NCHUNK) { item = s * NCHUNK + c; break; }
        }
        s_item = item;
    }
    __syncthreads();
    const int item = s_item;
    if (item < 0) return;                 // all work claimed
    const int s  = item >> 11;            // slice
    const int c0 = item & (NCHUNK - 1);   // first chunk (8-aligned)
    const int base_n = c0 * NODES_PER_CHUNK;   // 128 contiguous nodes

    // stage packed (cid,w) for all 128 nodes: 4096 uints, nt loads
    {
        const uintx4* src = (const uintx4*)(P + (size_t)base_n * EE);
#pragma unroll
        for (int i = 0; i < 4; ++i) {
            const uintx4 v = __builtin_nontemporal_load(src + i * 256 + tid);
            *(uintx4*)(s_pk + 4 * (i * 256 + tid)) = v;
        }
    }
    __syncthreads();

    const int wv = tid >> 6, lane = tid & 63;
    const int g = lane >> 3;              // child octet (lane bits 3..5)
    const int q = lane & 7;               // col-quad within slice
    const unsigned int* Gs = G + (size_t)s * SLICE_U32;

    for (int ch = 0; ch < CHUNKS_PER_CLAIM; ++ch) {
        for (int j = 0; j < 4; ++j) {
            const int nl = ch * NODES_PER_CHUNK + wv * 4 + j;
            float4 acc = make_float4(0.f, 0.f, 0.f, 0.f);
#pragma unroll
            for (int k = 0; k < 4; ++k) {
                const unsigned int pk = s_pk[nl * EE + k * 8 + g];
                const float w = __half2float(__ushort_as_half((unsigned short)(pk >> 16)));
                // 8 lanes (q=0..7) read one contiguous 32B row-slice
                const unsigned int u = Gs[(size_t)(pk & 0xFFFFu) * 8 + q];
                const floatx2 lo = __builtin_amdgcn_cvt_pk_f32_fp8(u, false);
                const floatx2 hi = __builtin_amdgcn_cvt_pk_f32_fp8(u, true);
                acc.x = fmaf(lo.x, w, acc.x);
                acc.y = fmaf(lo.y, w, acc.y);
                acc.z = fmaf(hi.x, w, acc.z);
                acc.w = fmaf(hi.y, w, acc.w);
            }
            // reduce over child octets (lane bits 3,4,5)
#pragma unroll
            for (int m = 8; m <= 32; m <<= 1) {
                acc.x += __shfl_xor(acc.x, m);
                acc.y += __shfl_xor(acc.y, m);
                acc.z += __shfl_xor(acc.z, m);
                acc.w += __shfl_xor(acc.w, m);
            }
            if (g == 0) {
                const int n = base_n + nl;
                floatx4 r;
                r.x = __logf(fmaxf(acc.x, 1e-10f));
                r.y = __logf(fmaxf(acc.y, 1e-10f));
                r.z = __logf(fmaxf(acc.z, 1e-10f));
                r.w = __logf(fmaxf(acc.w, 1e-10f));
                __builtin_nontemporal_store(r,
                    (floatx4*)(out + (size_t)nids[n] * BB + s * 32) + q);
            }
        }
    }
}

// ---- fallback (ws too small): standalone fp32 version ----
__global__ __launch_bounds__(256, 2)
void sum_layer_fallback(const float* __restrict__ element_mars,
                        const float* __restrict__ params,
                        const int* __restrict__ nids,
                        const int* __restrict__ cids,
                        const int* __restrict__ pids,
                        float* __restrict__ out)
{
    const int tid  = threadIdx.x;
    const int wave = tid >> 6;
    const int lane = tid & 63;

    __shared__ int   s_cid[4][EE];
    __shared__ float s_w[4][EE];
    if (tid < 4 * EE) {
        const int wi = tid >> 5, e = tid & (EE - 1);
        const int gn = blockIdx.x * 4 + wi;
        s_cid[wi][e] = cids[gn * EE + e];
        s_w[wi][e]   = params[pids[gn * EE + e]];
    }
    __syncthreads();

    const int n = blockIdx.x * 4 + wave;
    float4 acc = make_float4(0.f, 0.f, 0.f, 0.f);
#pragma unroll
    for (int e = 0; e < EE; ++e) {
        const float4 v = *reinterpret_cast<const float4*>(
            element_mars + (size_t)s_cid[wave][e] * BB + 4 * lane);
        const float w = s_w[wave][e];
        acc.x = fmaf(__expf(v.x), w, acc.x);
        acc.y = fmaf(__expf(v.y), w, acc.y);
        acc.z = fmaf(__expf(v.z), w, acc.z);
        acc.w = fmaf(__expf(v.w), w, acc.w);
    }
    float4 r;
    r.x = __logf(fmaxf(acc.x, 1e-10f));
    r.y = __logf(fmaxf(acc.y, 1e-10f));
    r.z = __logf(fmaxf(acc.z, 1e-10f));
    r.w = __logf(fmaxf(acc.w, 1e-10f));
    *reinterpret_cast<float4*>(out + (size_t)nids[n] * BB + 4 * lane) = r;
}

extern "C" void kernel_launch(void* const* d_in, const int* in_sizes, int n_in,
                              void* d_out, int out_size, void* d_ws, size_t ws_size,
                              hipStream_t stream) {
    // inputs: node_mars[N,B], element_mars[MAX_ELS,B], params[N*E],
    //         nids[N], cids[N,E], pids[N,E]
    const float* element_mars = (const float*)d_in[1];
    const float* params       = (const float*)d_in[2];
    const int*   nids         = (const int*)d_in[3];
    const int*   cids         = (const int*)d_in[4];
    const int*   pids         = (const int*)d_in[5];
    float*       out          = (float*)d_out;

    const size_t g_bytes = (size_t)MAX_ELS * BB;                    // 16MB fp8
    const size_t p_bytes = (size_t)NN * EE * sizeof(unsigned int);  // 4MB packed
    const size_t c_bytes = SLICES * CTR_STRIDE * sizeof(int);       // 1KB padded

    if (ws_size >= g_bytes + p_bytes + c_bytes) {
        unsigned int* G = (unsigned int*)d_ws;
        unsigned int* P = (unsigned int*)((char*)d_ws + g_bytes);
        int*        ctr = (int*)((char*)d_ws + g_bytes + p_bytes);

        zero_ctrs_kernel<<<1, SLICES * CTR_STRIDE, 0, stream>>>(ctr);
        exp_convert_kernel<<<(MAX_ELS * 64) / 256, 256, 0, stream>>>(
            (const float4*)element_mars, G);
        pack_kernel<<<(NN * EE) / 256, 256, 0, stream>>>(params, pids, cids, P);
        sum_main_kernel<<<NBLOCKS, 256, 0, stream>>>(G, P, nids, ctr, out);
    } else {
        sum_layer_fallback<<<NN / 4, 256, 0, stream>>>(
            element_mars, params, nids, cids, pids, out);
    }
}